// Round 1
// baseline (147.721 us; speedup 1.0000x reference)
//
#include <hip/hip_runtime.h>
#include <hip/hip_bf16.h>

// Problem constants (fixed by setup_inputs): B=4, S=8192, D=1024, E=64, top_k=1
#define NB 4
#define NS 8192
#define ND 1024
#define NE 64
#define NM (NB * NS)          // 32768 tokens
#define CAPACITY 640
#define CHUNK 512             // tokens per rank-chunk (divides NS)
#define NCHUNK (NM / CHUNK)   // 64 chunks total, 16 per batch

// ---------------------------------------------------------------------------
// K1: fp32 GEMM  logits[m][e] = sum_k x[m][k] * W[e][k]
// Tile: 128 tokens x 64 experts per block, K-step 64. 256 threads (4 waves).
// LDS rows padded to 68 floats (272 B) so strided reads spread across banks.
// Per-thread register tile: 8 tokens x 4 experts, float4 reads along k.
// ---------------------------------------------------------------------------
#define TM 128
#define TK 64
#define LDP 68   // padded row stride in floats (16B-aligned: 68*4=272)

__global__ __launch_bounds__(256) void k1_gemm(const float* __restrict__ x,
                                               const float* __restrict__ W,
                                               float* __restrict__ logits)
{
    __shared__ float xs[TM * LDP];   // 128 x 68 floats = 34816 B
    __shared__ float wsh[NE * LDP];  // 64 x 68 floats  = 17408 B

    const int tid = threadIdx.x;
    const int block_m = blockIdx.x * TM;
    const int ex = tid & 15;    // expert sub-index (0..15)
    const int ty = tid >> 4;    // token sub-index (0..15)

    float acc[8][4];
#pragma unroll
    for (int i = 0; i < 8; ++i)
#pragma unroll
        for (int j = 0; j < 4; ++j) acc[i][j] = 0.0f;

    const int lrow = tid >> 4;       // 0..15
    const int lcol = (tid & 15) * 4; // 0..60 step 4

    for (int k0 = 0; k0 < ND; k0 += TK) {
        // stage x tile: 128 rows x 64 cols
#pragma unroll
        for (int p = 0; p < 8; ++p) {
            int r = lrow + p * 16;
            float4 v = *(const float4*)(&x[(size_t)(block_m + r) * ND + k0 + lcol]);
            *(float4*)(&xs[r * LDP + lcol]) = v;
        }
        // stage W tile: 64 rows x 64 cols
#pragma unroll
        for (int p = 0; p < 4; ++p) {
            int r = lrow + p * 16;
            float4 v = *(const float4*)(&W[(size_t)r * ND + k0 + lcol]);
            *(float4*)(&wsh[r * LDP + lcol]) = v;
        }
        __syncthreads();

#pragma unroll
        for (int kk = 0; kk < TK; kk += 4) {
            float4 a[8], b[4];
#pragma unroll
            for (int i = 0; i < 8; ++i)
                a[i] = *(const float4*)(&xs[(i * 16 + ty) * LDP + kk]);
#pragma unroll
            for (int j = 0; j < 4; ++j)
                b[j] = *(const float4*)(&wsh[(j * 16 + ex) * LDP + kk]);
#pragma unroll
            for (int i = 0; i < 8; ++i)
#pragma unroll
                for (int j = 0; j < 4; ++j) {
                    acc[i][j] += a[i].x * b[j].x;
                    acc[i][j] += a[i].y * b[j].y;
                    acc[i][j] += a[i].z * b[j].z;
                    acc[i][j] += a[i].w * b[j].w;
                }
        }
        __syncthreads();
    }

    // write logits
#pragma unroll
    for (int i = 0; i < 8; ++i) {
        int t = block_m + i * 16 + ty;
#pragma unroll
        for (int j = 0; j < 4; ++j) {
            logits[(size_t)t * NE + j * 16 + ex] = acc[i][j];
        }
    }
}

// ---------------------------------------------------------------------------
// K2: per-token softmax top-1. One wave (64 lanes) per token, lane = expert.
// Writes argmax idx + top prob to ws; zeros the two sparse outputs.
// ---------------------------------------------------------------------------
__global__ __launch_bounds__(256) void k2_softmax(const float* __restrict__ logits,
                                                  float* __restrict__ e_out,
                                                  float* __restrict__ p_out,
                                                  int* __restrict__ idx_ws,
                                                  float* __restrict__ prob_ws)
{
    const int wave = threadIdx.x >> 6;
    const int lane = threadIdx.x & 63;
    const int token = blockIdx.x * 4 + wave;

    float v = logits[(size_t)token * NE + lane];

    // argmax reduce with lowest-index tie-break
    float m = v;
    int mi = lane;
#pragma unroll
    for (int off = 32; off > 0; off >>= 1) {
        float m2 = __shfl_down(m, off);
        int i2 = __shfl_down(mi, off);
        if (m2 > m || (m2 == m && i2 < mi)) { m = m2; mi = i2; }
    }
    m = __shfl(m, 0);
    mi = __shfl(mi, 0);

    float s = __expf(v - m);
#pragma unroll
    for (int off = 32; off > 0; off >>= 1) s += __shfl_down(s, off);
    s = __shfl(s, 0);

    if (lane == 0) {
        idx_ws[token] = mi;
        prob_ws[token] = 1.0f / s;   // prob of the argmax expert
    }
    // zero the sparse outputs (scatter kernel fills the nonzeros later)
    e_out[(size_t)token * NE + lane] = 0.0f;
    p_out[(size_t)token * NE + lane] = 0.0f;
}

// ---------------------------------------------------------------------------
// K3a: per-chunk expert histogram (order-independent)
// ---------------------------------------------------------------------------
__global__ __launch_bounds__(256) void k3a_hist(const int* __restrict__ idx_ws,
                                                int* __restrict__ hist)
{
    __shared__ int h[NE];
    const int c = blockIdx.x;
    if (threadIdx.x < NE) h[threadIdx.x] = 0;
    __syncthreads();
    const int t0 = c * CHUNK;
#pragma unroll
    for (int p = 0; p < CHUNK / 256; ++p) {
        int e = idx_ws[t0 + threadIdx.x + p * 256];
        atomicAdd(&h[e], 1);
    }
    __syncthreads();
    if (threadIdx.x < NE) hist[c * NE + threadIdx.x] = h[threadIdx.x];
}

// ---------------------------------------------------------------------------
// K3b: exclusive scan of chunk histograms along each batch's chunk sequence
// ---------------------------------------------------------------------------
__global__ __launch_bounds__(64) void k3b_scan(const int* __restrict__ hist,
                                               int* __restrict__ base)
{
    const int b = blockIdx.x;     // batch
    const int e = threadIdx.x;    // expert
    const int cpb = NS / CHUNK;   // chunks per batch = 16
    int run = 0;
    for (int c = 0; c < cpb; ++c) {
        int idx = (b * cpb + c) * NE + e;
        base[idx] = run;
        run += hist[idx];
    }
}

// ---------------------------------------------------------------------------
// K3c: per-chunk ordered rank + scatter. One wave per chunk; lane = expert.
// rank is INCLUSIVE (matches cumsum <= CAPACITY).
// ---------------------------------------------------------------------------
__global__ __launch_bounds__(64) void k3c_scatter(const int* __restrict__ idx_ws,
                                                  const float* __restrict__ prob_ws,
                                                  const int* __restrict__ base,
                                                  float* __restrict__ e_out,
                                                  float* __restrict__ p_out)
{
    __shared__ int sIdx[CHUNK];
    __shared__ float sProb[CHUNK];
    const int c = blockIdx.x;
    const int lane = threadIdx.x;
    const int t0 = c * CHUNK;
#pragma unroll
    for (int p = 0; p < CHUNK / 64; ++p) {
        sIdx[lane + p * 64] = idx_ws[t0 + lane + p * 64];
        sProb[lane + p * 64] = prob_ws[t0 + lane + p * 64];
    }
    __syncthreads();

    int counter = base[c * NE + lane];   // tokens assigned to this expert before chunk
    for (int j = 0; j < CHUNK; ++j) {
        int e = sIdx[j];
        bool mine = (lane == e);
        counter += mine ? 1 : 0;
        if (mine && counter <= CAPACITY) {
            size_t g = (size_t)(t0 + j) * NE + e;
            e_out[g] = 1.0f;
            p_out[g] = sProb[j];
        }
    }
}

// ---------------------------------------------------------------------------
extern "C" void kernel_launch(void* const* d_in, const int* in_sizes, int n_in,
                              void* d_out, int out_size, void* d_ws, size_t ws_size,
                              hipStream_t stream)
{
    const float* x = (const float*)d_in[0];   // [B,S,D] fp32
    const float* W = (const float*)d_in[1];   // [E,D] fp32
    // d_in[2] = top_k (==1), ignored

    float* out = (float*)d_out;
    float* e_out = out;                          // expert_indices as 0.0/1.0
    float* p_out = out + (size_t)NM * NE;        // router_probs
    float* logits = out + 2 * (size_t)NM * NE;   // logits

    char* ws = (char*)d_ws;
    int* idx_ws   = (int*)ws;                             // NM ints
    float* prob_ws = (float*)(ws + (size_t)NM * 4);       // NM floats
    int* hist     = (int*)(ws + (size_t)NM * 8);          // NCHUNK*NE
    int* base     = (int*)(ws + (size_t)NM * 8 + NCHUNK * NE * 4);

    k1_gemm<<<NM / TM, 256, 0, stream>>>(x, W, logits);
    k2_softmax<<<NM / 4, 256, 0, stream>>>(logits, e_out, p_out, idx_ws, prob_ws);
    k3a_hist<<<NCHUNK, 256, 0, stream>>>(idx_ws, hist);
    k3b_scan<<<NB, 64, 0, stream>>>(hist, base);
    k3c_scatter<<<NCHUNK, 64, 0, stream>>>(idx_ws, prob_ws, base, e_out, p_out);
}

// Round 2
// 104.393 us; speedup vs baseline: 1.4150x; 1.4150x over previous
//
#include <hip/hip_runtime.h>
#include <hip/hip_bf16.h>

// Problem constants (fixed by setup_inputs): B=4, S=8192, D=1024, E=64, top_k=1
#define NB 4
#define NS 8192
#define ND 1024
#define NE 64
#define NM (NB * NS)          // 32768 tokens
#define CAPACITY 640

#define TM 64                 // tokens per block == chunk size
#define TK 64                 // K-step
#define LDP 68                // padded LDS row stride (floats)
#define NCHUNK (NM / TM)      // 512 chunks
#define CPB (NS / TM)         // 128 chunks per batch

// ---------------------------------------------------------------------------
// K1 (fused): fp32 GEMM logits[m][e] = sum_k x[m][k]*W[e][k]
//   + per-token softmax top-1 (argmax idx, top prob)
//   + zero-fill of the two sparse outputs
//   + per-chunk (== per-block) expert histogram
// 256 threads, tile 64 tokens x 64 experts, per-thread 4x4 outputs.
// K-accumulation order kept identical to the r1-passing kernel (bitwise-same
// logits => same argmax ties resolution).
// ---------------------------------------------------------------------------
__global__ __launch_bounds__(256) void k1_fused(const float* __restrict__ x,
                                                const float* __restrict__ W,
                                                float* __restrict__ logits,
                                                float* __restrict__ e_out,
                                                float* __restrict__ p_out,
                                                int* __restrict__ idx_ws,
                                                float* __restrict__ prob_ws,
                                                int* __restrict__ hist)
{
    __shared__ float xs[TM * LDP];   // 17408 B
    __shared__ float wsh[NE * LDP];  // 17408 B
    __shared__ int lh[NE];

    const int tid = threadIdx.x;
    const int block_m = blockIdx.x * TM;
    const int ex = tid & 15;    // expert sub-index (0..15)
    const int ty = tid >> 4;    // token sub-index (0..15)

    if (tid < NE) lh[tid] = 0;

    float acc[4][4];
#pragma unroll
    for (int i = 0; i < 4; ++i)
#pragma unroll
        for (int j = 0; j < 4; ++j) acc[i][j] = 0.0f;

    const int lrow = tid >> 4;       // 0..15
    const int lcol = (tid & 15) * 4; // 0..60 step 4

    for (int k0 = 0; k0 < ND; k0 += TK) {
        // stage x tile: 64 rows x 64 cols
#pragma unroll
        for (int p = 0; p < 4; ++p) {
            int r = lrow + p * 16;
            float4 v = *(const float4*)(&x[(size_t)(block_m + r) * ND + k0 + lcol]);
            *(float4*)(&xs[r * LDP + lcol]) = v;
        }
        // stage W tile: 64 rows x 64 cols
#pragma unroll
        for (int p = 0; p < 4; ++p) {
            int r = lrow + p * 16;
            float4 v = *(const float4*)(&W[(size_t)r * ND + k0 + lcol]);
            *(float4*)(&wsh[r * LDP + lcol]) = v;
        }
        __syncthreads();

#pragma unroll
        for (int kk = 0; kk < TK; kk += 4) {
            float4 a[4], b[4];
#pragma unroll
            for (int i = 0; i < 4; ++i)
                a[i] = *(const float4*)(&xs[(i * 16 + ty) * LDP + kk]);
#pragma unroll
            for (int j = 0; j < 4; ++j)
                b[j] = *(const float4*)(&wsh[(j * 16 + ex) * LDP + kk]);
#pragma unroll
            for (int i = 0; i < 4; ++i)
#pragma unroll
                for (int j = 0; j < 4; ++j) {
                    acc[i][j] += a[i].x * b[j].x;
                    acc[i][j] += a[i].y * b[j].y;
                    acc[i][j] += a[i].z * b[j].z;
                    acc[i][j] += a[i].w * b[j].w;
                }
        }
        __syncthreads();
    }

    // ---- fused epilogue: per-token softmax top-1 over the 16-lane ex group
#pragma unroll
    for (int i = 0; i < 4; ++i) {
        const int t = block_m + i * 16 + ty;

        // local max over j (strict > keeps lowest expert index on ties)
        float m = acc[i][0];
        int mi = ex;
#pragma unroll
        for (int j = 1; j < 4; ++j) {
            if (acc[i][j] > m) { m = acc[i][j]; mi = j * 16 + ex; }
        }
        // butterfly across the 16 ex lanes (xor offsets stay in low 4 bits)
#pragma unroll
        for (int off = 1; off < 16; off <<= 1) {
            float m2 = __shfl_xor(m, off);
            int mi2 = __shfl_xor(mi, off);
            if (m2 > m || (m2 == m && mi2 < mi)) { m = m2; mi = mi2; }
        }
        // softmax denominator
        float s = 0.0f;
#pragma unroll
        for (int j = 0; j < 4; ++j) s += __expf(acc[i][j] - m);
#pragma unroll
        for (int off = 1; off < 16; off <<= 1) s += __shfl_xor(s, off);

        // write logits + zero the sparse outputs
#pragma unroll
        for (int j = 0; j < 4; ++j) {
            size_t g = (size_t)t * NE + j * 16 + ex;
            logits[g] = acc[i][j];
            e_out[g] = 0.0f;
            p_out[g] = 0.0f;
        }
        if (ex == 0) {
            idx_ws[t] = mi;
            prob_ws[t] = 1.0f / s;   // exp(max - max)/s
            atomicAdd(&lh[mi], 1);
        }
    }
    __syncthreads();
    if (tid < NE) hist[blockIdx.x * NE + tid] = lh[tid];
}

// ---------------------------------------------------------------------------
// K2: exclusive scan of per-chunk histograms along each batch's 128 chunks
// ---------------------------------------------------------------------------
__global__ __launch_bounds__(64) void k_scan(const int* __restrict__ hist,
                                             int* __restrict__ base)
{
    const int b = blockIdx.x;     // batch
    const int e = threadIdx.x;    // expert
    int run = 0;
    for (int c = 0; c < CPB; ++c) {
        int idx = (b * CPB + c) * NE + e;
        base[idx] = run;
        run += hist[idx];
    }
}

// ---------------------------------------------------------------------------
// K3: per-chunk ordered rank + scatter. One wave per 64-token chunk.
// rank is INCLUSIVE (matches cumsum <= CAPACITY).
// ---------------------------------------------------------------------------
__global__ __launch_bounds__(64) void k_scatter(const int* __restrict__ idx_ws,
                                                const float* __restrict__ prob_ws,
                                                const int* __restrict__ base,
                                                float* __restrict__ e_out,
                                                float* __restrict__ p_out)
{
    __shared__ int sIdx[TM];
    __shared__ float sProb[TM];
    const int c = blockIdx.x;
    const int lane = threadIdx.x;
    const int t0 = c * TM;
    sIdx[lane] = idx_ws[t0 + lane];
    sProb[lane] = prob_ws[t0 + lane];
    __syncthreads();

    int counter = base[c * NE + lane];
    for (int j = 0; j < TM; ++j) {
        if (sIdx[j] == lane) {
            ++counter;
            if (counter <= CAPACITY) {
                size_t g = (size_t)(t0 + j) * NE + lane;
                e_out[g] = 1.0f;
                p_out[g] = sProb[j];
            }
        }
    }
}

// ---------------------------------------------------------------------------
extern "C" void kernel_launch(void* const* d_in, const int* in_sizes, int n_in,
                              void* d_out, int out_size, void* d_ws, size_t ws_size,
                              hipStream_t stream)
{
    const float* x = (const float*)d_in[0];   // [B,S,D] fp32
    const float* W = (const float*)d_in[1];   // [E,D] fp32
    // d_in[2] = top_k (==1), ignored

    float* out = (float*)d_out;
    float* e_out = out;                          // expert_indices as 0.0/1.0
    float* p_out = out + (size_t)NM * NE;        // router_probs
    float* logits = out + 2 * (size_t)NM * NE;   // logits

    char* ws = (char*)d_ws;
    int* idx_ws    = (int*)ws;                                  // NM ints
    float* prob_ws = (float*)(ws + (size_t)NM * 4);             // NM floats
    int* hist      = (int*)(ws + (size_t)NM * 8);               // NCHUNK*NE
    int* base      = (int*)(ws + (size_t)NM * 8 + (size_t)NCHUNK * NE * 4);

    k1_fused<<<NM / TM, 256, 0, stream>>>(x, W, logits, e_out, p_out,
                                          idx_ws, prob_ws, hist);
    k_scan<<<NB, 64, 0, stream>>>(hist, base);
    k_scatter<<<NCHUNK, 64, 0, stream>>>(idx_ws, prob_ws, base, e_out, p_out);
}

// Round 3
// 102.048 us; speedup vs baseline: 1.4476x; 1.0230x over previous
//
#include <hip/hip_runtime.h>
#include <hip/hip_bf16.h>

// Problem constants (fixed by setup_inputs): B=4, S=8192, D=1024, E=64, top_k=1
#define NB 4
#define NS 8192
#define ND 1024
#define NE 64
#define NM (NB * NS)          // 32768 tokens
#define CAPACITY 640

#define TM 64                 // tokens per block == chunk size
#define NCHUNK (NM / TM)      // 512 chunks
#define CPB (NS / TM)         // 128 chunks per batch

typedef short short8 __attribute__((ext_vector_type(8)));
typedef float f32x4 __attribute__((ext_vector_type(4)));

// ---------------------------------------------------------------------------
// K0: split W (fp32 [E][D]) into bf16 hi/lo planes (RNE both levels).
// 65536 elements; 64 blocks x 256 threads x 4 elems.
// ---------------------------------------------------------------------------
__global__ __launch_bounds__(256) void w_conv(const float* __restrict__ W,
                                              unsigned short* __restrict__ Wh,
                                              unsigned short* __restrict__ Wl)
{
    const int i = (blockIdx.x * 256 + threadIdx.x) * 4;
    float4 v = *(const float4*)(W + i);
    float f[4] = {v.x, v.y, v.z, v.w};
    ushort4 h, l;
    unsigned short* hp = &h.x;
    unsigned short* lp = &l.x;
#pragma unroll
    for (int c = 0; c < 4; ++c) {
        __hip_bfloat16 hb = __float2bfloat16(f[c]);
        float r = f[c] - __bfloat162float(hb);
        __hip_bfloat16 lb = __float2bfloat16(r);
        hp[c] = __builtin_bit_cast(unsigned short, hb);
        lp[c] = __builtin_bit_cast(unsigned short, lb);
    }
    *(ushort4*)(Wh + i) = h;
    *(ushort4*)(Wl + i) = l;
}

// ---------------------------------------------------------------------------
// K1: zero-LDS bf16x3-split MFMA GEMM + fused softmax-top1 epilogue.
// Block: 256 threads = 4 waves; wave w owns tokens [block*64 + w*16, +16).
// Per wave per k-step(32): A-frag (x, split in-register) hi/lo,
// B-frags = 4 expert groups x hi/lo loaded straight from L2-resident Wh/Wl.
// acc[j] += Ah*Bh[j] + Ah*Bl[j] + Al*Bh[j]  (fp32 MFMA accumulate).
// C/D layout (verified m89/m91): col = lane&15 (expert), row = (lane>>4)*4+reg.
// ---------------------------------------------------------------------------
__global__ __launch_bounds__(256) void k1_mfma(const float* __restrict__ x,
                                               const short* __restrict__ Wh,
                                               const short* __restrict__ Wl,
                                               float* __restrict__ logits,
                                               float* __restrict__ e_out,
                                               float* __restrict__ p_out,
                                               int* __restrict__ idx_ws,
                                               float* __restrict__ prob_ws,
                                               int* __restrict__ hist)
{
    __shared__ int lh[NE];

    const int tid = threadIdx.x;
    const int lane = tid & 63;
    const int wv = tid >> 6;                    // wave 0..3
    const int lr = lane & 15;                   // fragment row/col index
    const int kq = lane >> 4;                   // k-quadrant 0..3
    const int tok_base = blockIdx.x * TM + wv * 16;

    if (tid < NE) lh[tid] = 0;

    const float* xrow = x + (size_t)(tok_base + lr) * ND + kq * 8;
    const short* wh0 = Wh + (size_t)lr * ND + kq * 8;
    const short* wl0 = Wl + (size_t)lr * ND + kq * 8;

    f32x4 acc[4];
#pragma unroll
    for (int j = 0; j < 4; ++j) acc[j] = (f32x4){0.f, 0.f, 0.f, 0.f};

    for (int k0 = 0; k0 < ND; k0 += 32) {
        // A: 8 fp32 of this lane's fragment, split to bf16 hi/lo in-register
        float4 v0 = *(const float4*)(xrow + k0);
        float4 v1 = *(const float4*)(xrow + k0 + 4);
        float f[8] = {v0.x, v0.y, v0.z, v0.w, v1.x, v1.y, v1.z, v1.w};
        short8 ah, al;
#pragma unroll
        for (int c = 0; c < 8; ++c) {
            __hip_bfloat16 hb = __float2bfloat16(f[c]);
            float r = f[c] - __bfloat162float(hb);
            __hip_bfloat16 lb = __float2bfloat16(r);
            ah[c] = __builtin_bit_cast(short, hb);
            al[c] = __builtin_bit_cast(short, lb);
        }
        // B: 4 expert groups, hi+lo, straight from global (L2-resident)
        short8 bh[4], bl[4];
#pragma unroll
        for (int j = 0; j < 4; ++j) {
            bh[j] = *(const short8*)(wh0 + (size_t)(j * 16) * ND + k0);
            bl[j] = *(const short8*)(wl0 + (size_t)(j * 16) * ND + k0);
        }
#pragma unroll
        for (int j = 0; j < 4; ++j) {
            acc[j] = __builtin_amdgcn_mfma_f32_16x16x32_bf16(ah, bh[j], acc[j], 0, 0, 0);
            acc[j] = __builtin_amdgcn_mfma_f32_16x16x32_bf16(ah, bl[j], acc[j], 0, 0, 0);
            acc[j] = __builtin_amdgcn_mfma_f32_16x16x32_bf16(al, bh[j], acc[j], 0, 0, 0);
        }
    }

    __syncthreads();   // lh zero-init visible before epilogue atomics

    // ---- fused epilogue: per-token softmax top-1
    // lane holds logits[t_r][j*16 + lr] for t_r = tok_base + kq*4 + r
#pragma unroll
    for (int r = 0; r < 4; ++r) {
        const int t = tok_base + kq * 4 + r;
        float val[4];
#pragma unroll
        for (int j = 0; j < 4; ++j) val[j] = acc[j][r];

        // local argmax over j (ascending j + strict > keeps lowest expert)
        float m = val[0];
        int mi = lr;
#pragma unroll
        for (int j = 1; j < 4; ++j) {
            if (val[j] > m) { m = val[j]; mi = j * 16 + lr; }
        }
        // butterfly across the 16 lanes of this fragment-row group
#pragma unroll
        for (int off = 1; off < 16; off <<= 1) {
            float m2 = __shfl_xor(m, off);
            int mi2 = __shfl_xor(mi, off);
            if (m2 > m || (m2 == m && mi2 < mi)) { m = m2; mi = mi2; }
        }
        // softmax denominator
        float s = 0.0f;
#pragma unroll
        for (int j = 0; j < 4; ++j) s += __expf(val[j] - m);
#pragma unroll
        for (int off = 1; off < 16; off <<= 1) s += __shfl_xor(s, off);

        // write logits + zero the sparse outputs
#pragma unroll
        for (int j = 0; j < 4; ++j) {
            size_t g = (size_t)t * NE + j * 16 + lr;
            logits[g] = val[j];
            e_out[g] = 0.0f;
            p_out[g] = 0.0f;
        }
        if (lr == 0) {
            idx_ws[t] = mi;
            prob_ws[t] = 1.0f / s;
            atomicAdd(&lh[mi], 1);
        }
    }
    __syncthreads();
    if (tid < NE) hist[blockIdx.x * NE + tid] = lh[tid];
}

// ---------------------------------------------------------------------------
// K2: exclusive scan of per-chunk histograms along each batch's 128 chunks
// ---------------------------------------------------------------------------
__global__ __launch_bounds__(64) void k_scan(const int* __restrict__ hist,
                                             int* __restrict__ base)
{
    const int b = blockIdx.x;     // batch
    const int e = threadIdx.x;    // expert
    int run = 0;
    for (int c = 0; c < CPB; ++c) {
        int idx = (b * CPB + c) * NE + e;
        base[idx] = run;
        run += hist[idx];
    }
}

// ---------------------------------------------------------------------------
// K3: per-chunk ordered rank + scatter. One wave per 64-token chunk.
// rank is INCLUSIVE (matches cumsum <= CAPACITY).
// ---------------------------------------------------------------------------
__global__ __launch_bounds__(64) void k_scatter(const int* __restrict__ idx_ws,
                                                const float* __restrict__ prob_ws,
                                                const int* __restrict__ base,
                                                float* __restrict__ e_out,
                                                float* __restrict__ p_out)
{
    __shared__ int sIdx[TM];
    __shared__ float sProb[TM];
    const int c = blockIdx.x;
    const int lane = threadIdx.x;
    const int t0 = c * TM;
    sIdx[lane] = idx_ws[t0 + lane];
    sProb[lane] = prob_ws[t0 + lane];
    __syncthreads();

    int counter = base[c * NE + lane];
    for (int j = 0; j < TM; ++j) {
        if (sIdx[j] == lane) {
            ++counter;
            if (counter <= CAPACITY) {
                size_t g = (size_t)(t0 + j) * NE + lane;
                e_out[g] = 1.0f;
                p_out[g] = sProb[j];
            }
        }
    }
}

// ---------------------------------------------------------------------------
extern "C" void kernel_launch(void* const* d_in, const int* in_sizes, int n_in,
                              void* d_out, int out_size, void* d_ws, size_t ws_size,
                              hipStream_t stream)
{
    const float* x = (const float*)d_in[0];   // [B,S,D] fp32
    const float* W = (const float*)d_in[1];   // [E,D] fp32
    // d_in[2] = top_k (==1), ignored

    float* out = (float*)d_out;
    float* e_out = out;                          // expert_indices as 0.0/1.0
    float* p_out = out + (size_t)NM * NE;        // router_probs
    float* logits = out + 2 * (size_t)NM * NE;   // logits

    char* ws = (char*)d_ws;
    int* idx_ws    = (int*)ws;                                   // NM ints   (128 KB)
    float* prob_ws = (float*)(ws + (size_t)NM * 4);              // NM floats (128 KB)
    int* hist      = (int*)(ws + (size_t)NM * 8);                // 512*64    (128 KB)
    int* base      = (int*)(ws + (size_t)NM * 8 + (size_t)NCHUNK * NE * 4); // (128 KB)
    unsigned short* Wh = (unsigned short*)(ws + (size_t)NM * 8 + (size_t)NCHUNK * NE * 8);
    unsigned short* Wl = Wh + (size_t)NE * ND;                   // 128 KB each

    w_conv<<<NE * ND / (256 * 4), 256, 0, stream>>>(W, Wh, Wl);
    k1_mfma<<<NM / TM, 256, 0, stream>>>(x, (const short*)Wh, (const short*)Wl,
                                         logits, e_out, p_out, idx_ws, prob_ws, hist);
    k_scan<<<NB, 64, 0, stream>>>(hist, base);
    k_scatter<<<NCHUNK, 64, 0, stream>>>(idx_ws, prob_ws, base, e_out, p_out);
}